// Round 5
// baseline (305.895 us; speedup 1.0000x reference)
//
#include <hip/hip_runtime.h>
#include <hip/hip_bf16.h>

// GAT encoder, 2 layers, MFMA GEMMs with fused attention-logit epilogue.
// L1: h1=x@W1^T (N,4,64) bf16 + as1/ad1; edge-softmax -> w1; act1=ELU(agg+b1) bf16.
// L2: h2=act1@W2^T (N,64) bf16 + as2/ad2; edge-softmax -> w2; out=agg+b2 fp32.
// N=50000, E=800000 (+N self-loops), K=256.

#define NEG_SLOPE 0.2f
#define SM_EPS 1e-16f

typedef unsigned short u16;
typedef unsigned int u32;
typedef __attribute__((ext_vector_type(8))) short short8v;
typedef __attribute__((ext_vector_type(4))) float f32x4;

__device__ __forceinline__ float bf2f(u16 u) { return __uint_as_float(((u32)u) << 16); }
__device__ __forceinline__ u16 f2bf(float f) {
  u32 u = __float_as_uint(f);
  u = (u + 0x7FFFu + ((u >> 16) & 1u)) >> 16;
  return (u16)u;
}
__device__ __forceinline__ float lrelu(float e) { return e > 0.f ? e : NEG_SLOPE * e; }

// ---------------- MFMA GEMM + fused attn-logit epilogue ----------------
// C[M][BN] = A[M][256] @ B[BN][256]^T (bf16 out), plus
// as[n](,h) = <C_row_head, a_src>, ad likewise (computed from fp32 acc).
// BM=64, BK=128, 4 waves (WGM x WGN). HEADS=4: head == wn (WN=64). HEADS=1: LDS reduce.
template <int BN, int WGM, int WGN, int ABF16, int HEADS>
__global__ __launch_bounds__(256, 2) void gemm_mfma(const void* __restrict__ Av,
                                                    const float* __restrict__ B,
                                                    u16* __restrict__ C,
                                                    const float* __restrict__ a_src,
                                                    const float* __restrict__ a_dst,
                                                    float* __restrict__ as_out,
                                                    float* __restrict__ ad_out, int M) {
  constexpr int K = 256, BK = 128, BM = 64;
  constexpr int WM = BM / WGM, WN = BN / WGN;
  constexpr int MF = WM / 16, NF = WN / 16;
  __shared__ short lds[(BM + BN) * BK];
  short* Al = lds;
  short* Bl = lds + BM * BK;
  const int t = threadIdx.x;
  const int wid = t >> 6, lane = t & 63;
  const int wm = wid / WGN, wn = wid % WGN;
  const int row0 = blockIdx.x * BM;
  const int l15 = lane & 15, l4 = lane >> 4;
  f32x4 acc[MF][NF] = {};
  for (int k0 = 0; k0 < K; k0 += BK) {
    for (int g = t; g < BM * 16; g += 256) {
      int row = g >> 4, c = g & 15;
      int gr = row0 + row;
      short8v v;
      if (ABF16) {
        if (gr < M)
          v = *reinterpret_cast<const short8v*>((const short*)Av + (size_t)gr * K + k0 + c * 8);
        else
          v = (short8v)(short)0;
      } else {
        if (gr < M) {
          const float* ap = (const float*)Av + (size_t)gr * K + k0 + c * 8;
          float4 f0 = *reinterpret_cast<const float4*>(ap);
          float4 f1 = *reinterpret_cast<const float4*>(ap + 4);
          v[0] = (short)f2bf(f0.x); v[1] = (short)f2bf(f0.y);
          v[2] = (short)f2bf(f0.z); v[3] = (short)f2bf(f0.w);
          v[4] = (short)f2bf(f1.x); v[5] = (short)f2bf(f1.y);
          v[6] = (short)f2bf(f1.z); v[7] = (short)f2bf(f1.w);
        } else {
          v = (short8v)(short)0;
        }
      }
      *reinterpret_cast<short8v*>(&Al[row * BK + ((c * 8) ^ ((row & 7) << 3))]) = v;
    }
    for (int g = t; g < BN * 16; g += 256) {
      int row = g >> 4, c = g & 15;
      const float* bp = B + (size_t)row * K + k0 + c * 8;
      float4 f0 = *reinterpret_cast<const float4*>(bp);
      float4 f1 = *reinterpret_cast<const float4*>(bp + 4);
      short8v v;
      v[0] = (short)f2bf(f0.x); v[1] = (short)f2bf(f0.y);
      v[2] = (short)f2bf(f0.z); v[3] = (short)f2bf(f0.w);
      v[4] = (short)f2bf(f1.x); v[5] = (short)f2bf(f1.y);
      v[6] = (short)f2bf(f1.z); v[7] = (short)f2bf(f1.w);
      *reinterpret_cast<short8v*>(&Bl[row * BK + ((c * 8) ^ ((row & 7) << 3))]) = v;
    }
    __syncthreads();
#pragma unroll
    for (int ks = 0; ks < BK / 32; ++ks) {
      short8v af[MF], bfr[NF];
#pragma unroll
      for (int fm = 0; fm < MF; ++fm) {
        int row = wm * WM + fm * 16 + l15;
        int col = (ks * 32 + l4 * 8) ^ ((row & 7) << 3);
        af[fm] = *reinterpret_cast<const short8v*>(&Al[row * BK + col]);
      }
#pragma unroll
      for (int fn = 0; fn < NF; ++fn) {
        int row = wn * WN + fn * 16 + l15;
        int col = (ks * 32 + l4 * 8) ^ ((row & 7) << 3);
        bfr[fn] = *reinterpret_cast<const short8v*>(&Bl[row * BK + col]);
      }
#pragma unroll
      for (int fm = 0; fm < MF; ++fm)
#pragma unroll
        for (int fn = 0; fn < NF; ++fn)
          acc[fm][fn] =
              __builtin_amdgcn_mfma_f32_16x16x32_bf16(af[fm], bfr[fn], acc[fm][fn], 0, 0, 0);
    }
    __syncthreads();
  }
  // C store (C/D layout: col=lane&15, row=(lane>>4)*4+r)
#pragma unroll
  for (int fm = 0; fm < MF; ++fm) {
#pragma unroll
    for (int fn = 0; fn < NF; ++fn) {
      int r0 = row0 + wm * WM + fm * 16 + l4 * 4;
      int col = wn * WN + fn * 16 + l15;
#pragma unroll
      for (int r = 0; r < 4; ++r)
        if (r0 + r < M) C[(size_t)(r0 + r) * BN + col] = f2bf(acc[fm][fn][r]);
    }
  }
  // fused attn logits from fp32 acc
  float asv[NF], adv[NF];
#pragma unroll
  for (int fn = 0; fn < NF; ++fn) {
    asv[fn] = a_src[wn * WN + fn * 16 + l15];
    adv[fn] = a_dst[wn * WN + fn * 16 + l15];
  }
  if (HEADS == 4) {
    // wave wn owns head wn (WN==64)
#pragma unroll
    for (int fm = 0; fm < MF; ++fm) {
#pragma unroll
      for (int r = 0; r < 4; ++r) {
        float ps = 0.f, pd = 0.f;
#pragma unroll
        for (int fn = 0; fn < NF; ++fn) {
          ps = fmaf(acc[fm][fn][r], asv[fn], ps);
          pd = fmaf(acc[fm][fn][r], adv[fn], pd);
        }
#pragma unroll
        for (int off = 1; off < 16; off <<= 1) {
          ps += __shfl_xor(ps, off);
          pd += __shfl_xor(pd, off);
        }
        if (l15 == 0) {
          int row = row0 + wm * WM + fm * 16 + l4 * 4 + r;
          if (row < M) {
            as_out[(size_t)row * 4 + wn] = ps;
            ad_out[(size_t)row * 4 + wn] = pd;
          }
        }
      }
    }
  } else {
    // HEADS==1: sum across the WGN col-strips via LDS
    float* redAs = (float*)lds;                       // [WGM][WGN][WM]
    float* redAd = redAs + WGM * WGN * WM;
#pragma unroll
    for (int fm = 0; fm < MF; ++fm) {
#pragma unroll
      for (int r = 0; r < 4; ++r) {
        float ps = 0.f, pd = 0.f;
#pragma unroll
        for (int fn = 0; fn < NF; ++fn) {
          ps = fmaf(acc[fm][fn][r], asv[fn], ps);
          pd = fmaf(acc[fm][fn][r], adv[fn], pd);
        }
#pragma unroll
        for (int off = 1; off < 16; off <<= 1) {
          ps += __shfl_xor(ps, off);
          pd += __shfl_xor(pd, off);
        }
        if (l15 == 0) {
          int rl = fm * 16 + l4 * 4 + r;
          redAs[(wm * WGN + wn) * WM + rl] = ps;
          redAd[(wm * WGN + wn) * WM + rl] = pd;
        }
      }
    }
    __syncthreads();
    if (t < BM) {
      int wmx = t / WM, rl = t % WM;
      float s = 0.f, d = 0.f;
      for (int w = 0; w < WGN; ++w) {
        s += redAs[(wmx * WGN + w) * WM + rl];
        d += redAd[(wmx * WGN + w) * WM + rl];
      }
      int row = row0 + t;
      if (row < M) {
        as_out[row] = s;
        ad_out[row] = d;
      }
    }
  }
}

// ---------------- CSR build ----------------
__global__ void count_kernel(const int* __restrict__ ei, int E, int N, int* __restrict__ counts) {
  int e = blockIdx.x * blockDim.x + threadIdx.x;
  if (e >= E + N) return;
  int d = (e < E) ? ei[E + e] : (e - E);
  atomicAdd(&counts[d], 1);
}

__global__ __launch_bounds__(256) void blocksum_kernel(const int* __restrict__ counts,
                                                       int* __restrict__ bsums, int N) {
  const int b = blockIdx.x, t = threadIdx.x;
  const int base = b * 1024 + t * 4;
  int s = 0;
#pragma unroll
  for (int i = 0; i < 4; ++i) {
    int idx = base + i;
    if (idx < N) s += counts[idx];
  }
#pragma unroll
  for (int off = 1; off < 64; off <<= 1) s += __shfl_xor(s, off);
  __shared__ int ws[4];
  if ((t & 63) == 0) ws[t >> 6] = s;
  __syncthreads();
  if (t == 0) bsums[b] = ws[0] + ws[1] + ws[2] + ws[3];
}

__global__ void scanbsums_kernel(int* __restrict__ bsums, int nb) {
  const int t = threadIdx.x;  // 64
  int carry = 0;
  for (int base = 0; base < nb; base += 64) {
    int i = base + t;
    int orig = (i < nb) ? bsums[i] : 0;
    int v = orig;
#pragma unroll
    for (int off = 1; off < 64; off <<= 1) {
      int u = __shfl_up(v, off);
      if (t >= off) v += u;
    }
    if (i < nb) bsums[i] = carry + v - orig;
    carry += __shfl(v, 63);
  }
}

__global__ __launch_bounds__(256) void scanfinal_kernel(const int* __restrict__ counts,
                                                        const int* __restrict__ boffs,
                                                        int* __restrict__ rowptr,
                                                        int* __restrict__ cursor, int N) {
  const int b = blockIdx.x, t = threadIdx.x;
  const int wave = t >> 6, lane = t & 63;
  const int base = b * 1024 + t * 4;
  int v[4];
#pragma unroll
  for (int i = 0; i < 4; ++i) {
    int idx = base + i;
    v[i] = (idx < N) ? counts[idx] : 0;
  }
  int ts = v[0] + v[1] + v[2] + v[3];
  int inc = ts;
#pragma unroll
  for (int off = 1; off < 64; off <<= 1) {
    int u = __shfl_up(inc, off);
    if (lane >= off) inc += u;
  }
  __shared__ int wsum[4];
  if (lane == 63) wsum[wave] = inc;
  __syncthreads();
  int woff = 0;
  for (int w = 0; w < 4; ++w)
    if (w < wave) woff += wsum[w];
  int run = boffs[b] + woff + (inc - ts);
#pragma unroll
  for (int i = 0; i < 4; ++i) {
    int idx = base + i;
    if (idx < N) {
      rowptr[idx] = run;
      cursor[idx] = run;
    }
    run += v[i];
  }
  if (N - 1 >= base && N - 1 < base + 4) rowptr[N] = run;
}

__global__ void scatter_kernel(const int* __restrict__ ei, int E, int N,
                               int* __restrict__ cursor, int* __restrict__ srcs) {
  int e = blockIdx.x * blockDim.x + threadIdx.x;
  if (e >= E + N) return;
  int s = (e < E) ? ei[e] : (e - E);
  int d = (e < E) ? ei[E + e] : (e - E);
  int pos = atomicAdd(&cursor[d], 1);
  srcs[pos] = s;
}

// ---------------- fused edge softmax (online), layer 1: thread per (n,h) ----------------
// writes final weights w1[j*4+h] = exp(e-m)/(sum+eps)
__global__ void esm1_kernel(const int* __restrict__ rowptr, const int* __restrict__ srcs,
                            const float* __restrict__ as1, const float* __restrict__ ad1,
                            float* __restrict__ w1, int N) {
  int gid = blockIdx.x * blockDim.x + threadIdx.x;
  if (gid >= N * 4) return;
  int n = gid >> 2, h = gid & 3;
  int beg = rowptr[n], end = rowptr[n + 1];
  float ad = ad1[(size_t)n * 4 + h];
  float m = -1e30f, s = 0.f;
  for (int j = beg; j < end; ++j) {
    float e = lrelu(as1[(size_t)srcs[j] * 4 + h] + ad);
    if (e <= m) {
      s += __expf(e - m);
    } else {
      s = s * __expf(m - e) + 1.f;
      m = e;
    }
  }
  float rs = 1.f / (s + SM_EPS);
  for (int j = beg; j < end; ++j) {
    float e = lrelu(as1[(size_t)srcs[j] * 4 + h] + ad);
    w1[(size_t)j * 4 + h] = __expf(e - m) * rs;
  }
}

// ---------------- fused edge softmax, layer 2: thread per n ----------------
__global__ void esm2_kernel(const int* __restrict__ rowptr, const int* __restrict__ srcs,
                            const float* __restrict__ as2, const float* __restrict__ ad2,
                            float* __restrict__ w2, int N) {
  int n = blockIdx.x * blockDim.x + threadIdx.x;
  if (n >= N) return;
  int beg = rowptr[n], end = rowptr[n + 1];
  float ad = ad2[n];
  float m = -1e30f, s = 0.f;
  for (int j = beg; j < end; ++j) {
    float e = lrelu(as2[srcs[j]] + ad);
    if (e <= m) {
      s += __expf(e - m);
    } else {
      s = s * __expf(m - e) + 1.f;
      m = e;
    }
  }
  float rs = 1.f / (s + SM_EPS);
  for (int j = beg; j < end; ++j) {
    float e = lrelu(as2[srcs[j]] + ad);
    w2[j] = __expf(e - m) * rs;
  }
}

// ---------------- layer-1 gather (bf16 h1 -> bf16 act1), w precomputed, 4-edge unroll ----
__global__ __launch_bounds__(256) void gather1_kernel(const u16* __restrict__ h1b,
                                                      const int* __restrict__ rowptr,
                                                      const int* __restrict__ srcs,
                                                      const float* __restrict__ w1,
                                                      const float* __restrict__ b1,
                                                      u16* __restrict__ act1b, int N) {
  const int wave = threadIdx.x >> 6, lane = threadIdx.x & 63;
  const int n = blockIdx.x * 4 + wave;
  if (n >= N) return;
  const int h = lane >> 4;
  const int beg = rowptr[n], end = rowptr[n + 1];
  float4 acc = make_float4(0.f, 0.f, 0.f, 0.f);
  int j = beg;
  for (; j + 3 < end; j += 4) {
    int s0 = srcs[j], s1 = srcs[j + 1], s2 = srcs[j + 2], s3 = srcs[j + 3];
    float w0 = w1[(size_t)j * 4 + h];
    float w1_ = w1[(size_t)(j + 1) * 4 + h];
    float w2_ = w1[(size_t)(j + 2) * 4 + h];
    float w3_ = w1[(size_t)(j + 3) * 4 + h];
    ushort4 v0 = *reinterpret_cast<const ushort4*>(&h1b[(size_t)s0 * 256 + lane * 4]);
    ushort4 v1 = *reinterpret_cast<const ushort4*>(&h1b[(size_t)s1 * 256 + lane * 4]);
    ushort4 v2 = *reinterpret_cast<const ushort4*>(&h1b[(size_t)s2 * 256 + lane * 4]);
    ushort4 v3 = *reinterpret_cast<const ushort4*>(&h1b[(size_t)s3 * 256 + lane * 4]);
    acc.x = fmaf(w0, bf2f(v0.x), acc.x); acc.y = fmaf(w0, bf2f(v0.y), acc.y);
    acc.z = fmaf(w0, bf2f(v0.z), acc.z); acc.w = fmaf(w0, bf2f(v0.w), acc.w);
    acc.x = fmaf(w1_, bf2f(v1.x), acc.x); acc.y = fmaf(w1_, bf2f(v1.y), acc.y);
    acc.z = fmaf(w1_, bf2f(v1.z), acc.z); acc.w = fmaf(w1_, bf2f(v1.w), acc.w);
    acc.x = fmaf(w2_, bf2f(v2.x), acc.x); acc.y = fmaf(w2_, bf2f(v2.y), acc.y);
    acc.z = fmaf(w2_, bf2f(v2.z), acc.z); acc.w = fmaf(w2_, bf2f(v2.w), acc.w);
    acc.x = fmaf(w3_, bf2f(v3.x), acc.x); acc.y = fmaf(w3_, bf2f(v3.y), acc.y);
    acc.z = fmaf(w3_, bf2f(v3.z), acc.z); acc.w = fmaf(w3_, bf2f(v3.w), acc.w);
  }
  for (; j < end; ++j) {
    int s0 = srcs[j];
    float w0 = w1[(size_t)j * 4 + h];
    ushort4 v0 = *reinterpret_cast<const ushort4*>(&h1b[(size_t)s0 * 256 + lane * 4]);
    acc.x = fmaf(w0, bf2f(v0.x), acc.x); acc.y = fmaf(w0, bf2f(v0.y), acc.y);
    acc.z = fmaf(w0, bf2f(v0.z), acc.z); acc.w = fmaf(w0, bf2f(v0.w), acc.w);
  }
  float4 bb = *reinterpret_cast<const float4*>(&b1[lane * 4]);
  float4 o;
  o.x = acc.x + bb.x; o.y = acc.y + bb.y; o.z = acc.z + bb.z; o.w = acc.w + bb.w;
  o.x = o.x > 0.f ? o.x : __expf(o.x) - 1.f;
  o.y = o.y > 0.f ? o.y : __expf(o.y) - 1.f;
  o.z = o.z > 0.f ? o.z : __expf(o.z) - 1.f;
  o.w = o.w > 0.f ? o.w : __expf(o.w) - 1.f;
  ushort4 ov;
  ov.x = f2bf(o.x); ov.y = f2bf(o.y); ov.z = f2bf(o.z); ov.w = f2bf(o.w);
  *reinterpret_cast<ushort4*>(&act1b[(size_t)n * 256 + lane * 4]) = ov;
}

// ---------------- layer-2 gather (bf16 h2): 4 edges x 16 lanes x 4ch, w precomputed ----
__global__ __launch_bounds__(256) void gather2_kernel(const u16* __restrict__ h2b,
                                                      const int* __restrict__ rowptr,
                                                      const int* __restrict__ srcs,
                                                      const float* __restrict__ w2,
                                                      const float* __restrict__ b2,
                                                      float* __restrict__ out, int N) {
  const int wave = threadIdx.x >> 6, lane = threadIdx.x & 63;
  const int n = blockIdx.x * 4 + wave;
  if (n >= N) return;
  const int g = lane >> 4;
  const int c4 = (lane & 15) * 4;
  const int beg = rowptr[n], end = rowptr[n + 1];
  float4 acc = make_float4(0.f, 0.f, 0.f, 0.f);
  for (int j0 = beg; j0 < end; j0 += 4) {
    int j = j0 + g;
    float w = 0.f;
    int s = 0;
    if (j < end) {
      s = srcs[j];
      w = w2[j];
    }
    ushort4 v = *reinterpret_cast<const ushort4*>(&h2b[(size_t)s * 64 + c4]);
    acc.x = fmaf(w, bf2f(v.x), acc.x); acc.y = fmaf(w, bf2f(v.y), acc.y);
    acc.z = fmaf(w, bf2f(v.z), acc.z); acc.w = fmaf(w, bf2f(v.w), acc.w);
  }
#pragma unroll
  for (int off = 16; off <= 32; off <<= 1) {
    acc.x += __shfl_xor(acc.x, off);
    acc.y += __shfl_xor(acc.y, off);
    acc.z += __shfl_xor(acc.z, off);
    acc.w += __shfl_xor(acc.w, off);
  }
  if (lane < 16) {
    float4 bb = *reinterpret_cast<const float4*>(&b2[c4]);
    float4 o = make_float4(acc.x + bb.x, acc.y + bb.y, acc.z + bb.z, acc.w + bb.w);
    *reinterpret_cast<float4*>(&out[(size_t)n * 64 + c4]) = o;
  }
}

extern "C" void kernel_launch(void* const* d_in, const int* in_sizes, int n_in,
                              void* d_out, int out_size, void* d_ws, size_t ws_size,
                              hipStream_t stream) {
  const float* x      = (const float*)d_in[0];
  const int*   ei     = (const int*)d_in[1];
  const float* W1     = (const float*)d_in[2];
  const float* a_src1 = (const float*)d_in[3];
  const float* a_dst1 = (const float*)d_in[4];
  const float* b1     = (const float*)d_in[5];
  const float* W2     = (const float*)d_in[6];
  const float* a_src2 = (const float*)d_in[7];
  const float* a_dst2 = (const float*)d_in[8];
  const float* b2     = (const float*)d_in[9];
  float* out = (float*)d_out;

  const int N = in_sizes[0] / 256;  // 50000
  const int E = in_sizes[1] / 2;    // 800000
  const int Etot = E + N;

  char* ws = (char*)d_ws;
  size_t off = 0;
  auto alloc = [&](size_t bytes) -> void* {
    off = (off + 255) & ~(size_t)255;
    void* p = ws + off;
    off += bytes;
    return p;
  };
  u16*   h1b    = (u16*)alloc((size_t)N * 256 * 2);
  u16*   act1b  = (u16*)alloc((size_t)N * 256 * 2);
  u16*   h2b    = (u16*)alloc((size_t)N * 64 * 2);
  float* as1    = (float*)alloc((size_t)N * 4 * 4);
  float* ad1    = (float*)alloc((size_t)N * 4 * 4);
  float* w1     = (float*)alloc((size_t)Etot * 4 * 4);
  int*   counts = (int*)alloc((size_t)N * 4);
  int*   rowptr = (int*)alloc((size_t)(N + 1) * 4);
  int*   cursor = (int*)alloc((size_t)N * 4);
  int*   srcs   = (int*)alloc((size_t)Etot * 4);
  int*   bsums  = (int*)alloc((size_t)256 * 4);
  // layer-2 aliases (layer-1 versions dead by then)
  float* as2 = as1;
  float* ad2 = ad1;
  float* w2  = w1;
  (void)ws_size; (void)n_in; (void)out_size;

  // CSR build
  hipMemsetAsync(counts, 0, (size_t)N * 4, stream);
  int eblocks = (Etot + 255) / 256;
  count_kernel<<<eblocks, 256, 0, stream>>>(ei, E, N, counts);
  const int nb = (N + 1023) / 1024;
  blocksum_kernel<<<nb, 256, 0, stream>>>(counts, bsums, N);
  scanbsums_kernel<<<1, 64, 0, stream>>>(bsums, nb);
  scanfinal_kernel<<<nb, 256, 0, stream>>>(counts, bsums, rowptr, cursor, N);
  scatter_kernel<<<eblocks, 256, 0, stream>>>(ei, E, N, cursor, srcs);

  const int gblocks = (N + 63) / 64;

  // Layer 1
  gemm_mfma<256, 1, 4, 0, 4><<<gblocks, 256, 0, stream>>>(x, W1, h1b, a_src1, a_dst1,
                                                          as1, ad1, N);
  esm1_kernel<<<(N * 4 + 255) / 256, 256, 0, stream>>>(rowptr, srcs, as1, ad1, w1, N);
  gather1_kernel<<<(N + 3) / 4, 256, 0, stream>>>(h1b, rowptr, srcs, w1, b1, act1b, N);

  // Layer 2
  gemm_mfma<64, 2, 2, 1, 1><<<gblocks, 256, 0, stream>>>(act1b, W2, h2b, a_src2, a_dst2,
                                                         as2, ad2, N);
  esm2_kernel<<<(N + 255) / 256, 256, 0, stream>>>(rowptr, srcs, as2, ad2, w2, N);
  gather2_kernel<<<(N + 3) / 4, 256, 0, stream>>>(h2b, rowptr, srcs, w2, b2, out, N);
}

// Round 6
// 287.264 us; speedup vs baseline: 1.0649x; 1.0649x over previous
//
#include <hip/hip_runtime.h>
#include <hip/hip_bf16.h>

// GAT encoder, 2 layers, MFMA GEMMs with fused attn-logit epilogue, and
// gathers with fully fused segment-softmax (no per-edge weight buffers).
// L1: h1=x@W1^T (N,4,64) bf16 + as1/ad1; gather1: softmax+agg+b1+ELU -> act1 bf16.
// L2: h2=act1@W2^T (N,64) bf16 + as2/ad2; gather2: softmax+agg+b2 -> out fp32.
// N=50000, E=800000 (+N self-loops), K=256.

#define NEG_SLOPE 0.2f
#define SM_EPS 1e-16f

typedef unsigned short u16;
typedef unsigned int u32;
typedef __attribute__((ext_vector_type(8))) short short8v;
typedef __attribute__((ext_vector_type(4))) float f32x4;

__device__ __forceinline__ float bf2f(u16 u) { return __uint_as_float(((u32)u) << 16); }
__device__ __forceinline__ u16 f2bf(float f) {
  u32 u = __float_as_uint(f);
  u = (u + 0x7FFFu + ((u >> 16) & 1u)) >> 16;
  return (u16)u;
}
__device__ __forceinline__ float lrelu(float e) { return e > 0.f ? e : NEG_SLOPE * e; }

// ---------------- MFMA GEMM + fused attn-logit epilogue ----------------
template <int BN, int WGM, int WGN, int ABF16, int HEADS>
__global__ __launch_bounds__(256, 2) void gemm_mfma(const void* __restrict__ Av,
                                                    const float* __restrict__ B,
                                                    u16* __restrict__ C,
                                                    const float* __restrict__ a_src,
                                                    const float* __restrict__ a_dst,
                                                    float* __restrict__ as_out,
                                                    float* __restrict__ ad_out, int M) {
  constexpr int K = 256, BK = 128, BM = 64;
  constexpr int WM = BM / WGM, WN = BN / WGN;
  constexpr int MF = WM / 16, NF = WN / 16;
  __shared__ short lds[(BM + BN) * BK];
  short* Al = lds;
  short* Bl = lds + BM * BK;
  const int t = threadIdx.x;
  const int wid = t >> 6, lane = t & 63;
  const int wm = wid / WGN, wn = wid % WGN;
  const int row0 = blockIdx.x * BM;
  const int l15 = lane & 15, l4 = lane >> 4;
  f32x4 acc[MF][NF] = {};
  for (int k0 = 0; k0 < K; k0 += BK) {
    for (int g = t; g < BM * 16; g += 256) {
      int row = g >> 4, c = g & 15;
      int gr = row0 + row;
      short8v v;
      if (ABF16) {
        if (gr < M)
          v = *reinterpret_cast<const short8v*>((const short*)Av + (size_t)gr * K + k0 + c * 8);
        else
          v = (short8v)(short)0;
      } else {
        if (gr < M) {
          const float* ap = (const float*)Av + (size_t)gr * K + k0 + c * 8;
          float4 f0 = *reinterpret_cast<const float4*>(ap);
          float4 f1 = *reinterpret_cast<const float4*>(ap + 4);
          v[0] = (short)f2bf(f0.x); v[1] = (short)f2bf(f0.y);
          v[2] = (short)f2bf(f0.z); v[3] = (short)f2bf(f0.w);
          v[4] = (short)f2bf(f1.x); v[5] = (short)f2bf(f1.y);
          v[6] = (short)f2bf(f1.z); v[7] = (short)f2bf(f1.w);
        } else {
          v = (short8v)(short)0;
        }
      }
      *reinterpret_cast<short8v*>(&Al[row * BK + ((c * 8) ^ ((row & 7) << 3))]) = v;
    }
    for (int g = t; g < BN * 16; g += 256) {
      int row = g >> 4, c = g & 15;
      const float* bp = B + (size_t)row * K + k0 + c * 8;
      float4 f0 = *reinterpret_cast<const float4*>(bp);
      float4 f1 = *reinterpret_cast<const float4*>(bp + 4);
      short8v v;
      v[0] = (short)f2bf(f0.x); v[1] = (short)f2bf(f0.y);
      v[2] = (short)f2bf(f0.z); v[3] = (short)f2bf(f0.w);
      v[4] = (short)f2bf(f1.x); v[5] = (short)f2bf(f1.y);
      v[6] = (short)f2bf(f1.z); v[7] = (short)f2bf(f1.w);
      *reinterpret_cast<short8v*>(&Bl[row * BK + ((c * 8) ^ ((row & 7) << 3))]) = v;
    }
    __syncthreads();
#pragma unroll
    for (int ks = 0; ks < BK / 32; ++ks) {
      short8v af[MF], bfr[NF];
#pragma unroll
      for (int fm = 0; fm < MF; ++fm) {
        int row = wm * WM + fm * 16 + l15;
        int col = (ks * 32 + l4 * 8) ^ ((row & 7) << 3);
        af[fm] = *reinterpret_cast<const short8v*>(&Al[row * BK + col]);
      }
#pragma unroll
      for (int fn = 0; fn < NF; ++fn) {
        int row = wn * WN + fn * 16 + l15;
        int col = (ks * 32 + l4 * 8) ^ ((row & 7) << 3);
        bfr[fn] = *reinterpret_cast<const short8v*>(&Bl[row * BK + col]);
      }
#pragma unroll
      for (int fm = 0; fm < MF; ++fm)
#pragma unroll
        for (int fn = 0; fn < NF; ++fn)
          acc[fm][fn] =
              __builtin_amdgcn_mfma_f32_16x16x32_bf16(af[fm], bfr[fn], acc[fm][fn], 0, 0, 0);
    }
    __syncthreads();
  }
#pragma unroll
  for (int fm = 0; fm < MF; ++fm) {
#pragma unroll
    for (int fn = 0; fn < NF; ++fn) {
      int r0 = row0 + wm * WM + fm * 16 + l4 * 4;
      int col = wn * WN + fn * 16 + l15;
#pragma unroll
      for (int r = 0; r < 4; ++r)
        if (r0 + r < M) C[(size_t)(r0 + r) * BN + col] = f2bf(acc[fm][fn][r]);
    }
  }
  float asv[NF], adv[NF];
#pragma unroll
  for (int fn = 0; fn < NF; ++fn) {
    asv[fn] = a_src[wn * WN + fn * 16 + l15];
    adv[fn] = a_dst[wn * WN + fn * 16 + l15];
  }
  if (HEADS == 4) {
#pragma unroll
    for (int fm = 0; fm < MF; ++fm) {
#pragma unroll
      for (int r = 0; r < 4; ++r) {
        float ps = 0.f, pd = 0.f;
#pragma unroll
        for (int fn = 0; fn < NF; ++fn) {
          ps = fmaf(acc[fm][fn][r], asv[fn], ps);
          pd = fmaf(acc[fm][fn][r], adv[fn], pd);
        }
#pragma unroll
        for (int off = 1; off < 16; off <<= 1) {
          ps += __shfl_xor(ps, off);
          pd += __shfl_xor(pd, off);
        }
        if (l15 == 0) {
          int row = row0 + wm * WM + fm * 16 + l4 * 4 + r;
          if (row < M) {
            as_out[(size_t)row * 4 + wn] = ps;
            ad_out[(size_t)row * 4 + wn] = pd;
          }
        }
      }
    }
  } else {
    float* redAs = (float*)lds;
    float* redAd = redAs + WGM * WGN * WM;
#pragma unroll
    for (int fm = 0; fm < MF; ++fm) {
#pragma unroll
      for (int r = 0; r < 4; ++r) {
        float ps = 0.f, pd = 0.f;
#pragma unroll
        for (int fn = 0; fn < NF; ++fn) {
          ps = fmaf(acc[fm][fn][r], asv[fn], ps);
          pd = fmaf(acc[fm][fn][r], adv[fn], pd);
        }
#pragma unroll
        for (int off = 1; off < 16; off <<= 1) {
          ps += __shfl_xor(ps, off);
          pd += __shfl_xor(pd, off);
        }
        if (l15 == 0) {
          int rl = fm * 16 + l4 * 4 + r;
          redAs[(wm * WGN + wn) * WM + rl] = ps;
          redAd[(wm * WGN + wn) * WM + rl] = pd;
        }
      }
    }
    __syncthreads();
    if (t < BM) {
      int wmx = t / WM, rl = t % WM;
      float s = 0.f, d = 0.f;
      for (int w = 0; w < WGN; ++w) {
        s += redAs[(wmx * WGN + w) * WM + rl];
        d += redAd[(wmx * WGN + w) * WM + rl];
      }
      int row = row0 + t;
      if (row < M) {
        as_out[row] = s;
        ad_out[row] = d;
      }
    }
  }
}

// ---------------- CSR build ----------------
__global__ void count_kernel(const int* __restrict__ ei, int E, int N, int* __restrict__ counts) {
  int e = blockIdx.x * blockDim.x + threadIdx.x;
  if (e >= E + N) return;
  int d = (e < E) ? ei[E + e] : (e - E);
  atomicAdd(&counts[d], 1);
}

__global__ __launch_bounds__(256) void blocksum_kernel(const int* __restrict__ counts,
                                                       int* __restrict__ bsums, int N) {
  const int b = blockIdx.x, t = threadIdx.x;
  const int base = b * 1024 + t * 4;
  int s = 0;
#pragma unroll
  for (int i = 0; i < 4; ++i) {
    int idx = base + i;
    if (idx < N) s += counts[idx];
  }
#pragma unroll
  for (int off = 1; off < 64; off <<= 1) s += __shfl_xor(s, off);
  __shared__ int ws[4];
  if ((t & 63) == 0) ws[t >> 6] = s;
  __syncthreads();
  if (t == 0) bsums[b] = ws[0] + ws[1] + ws[2] + ws[3];
}

__global__ void scanbsums_kernel(int* __restrict__ bsums, int nb) {
  const int t = threadIdx.x;  // 64
  int carry = 0;
  for (int base = 0; base < nb; base += 64) {
    int i = base + t;
    int orig = (i < nb) ? bsums[i] : 0;
    int v = orig;
#pragma unroll
    for (int off = 1; off < 64; off <<= 1) {
      int u = __shfl_up(v, off);
      if (t >= off) v += u;
    }
    if (i < nb) bsums[i] = carry + v - orig;
    carry += __shfl(v, 63);
  }
}

__global__ __launch_bounds__(256) void scanfinal_kernel(const int* __restrict__ counts,
                                                        const int* __restrict__ boffs,
                                                        int* __restrict__ rowptr,
                                                        int* __restrict__ cursor, int N) {
  const int b = blockIdx.x, t = threadIdx.x;
  const int wave = t >> 6, lane = t & 63;
  const int base = b * 1024 + t * 4;
  int v[4];
#pragma unroll
  for (int i = 0; i < 4; ++i) {
    int idx = base + i;
    v[i] = (idx < N) ? counts[idx] : 0;
  }
  int ts = v[0] + v[1] + v[2] + v[3];
  int inc = ts;
#pragma unroll
  for (int off = 1; off < 64; off <<= 1) {
    int u = __shfl_up(inc, off);
    if (lane >= off) inc += u;
  }
  __shared__ int wsum[4];
  if (lane == 63) wsum[wave] = inc;
  __syncthreads();
  int woff = 0;
  for (int w = 0; w < 4; ++w)
    if (w < wave) woff += wsum[w];
  int run = boffs[b] + woff + (inc - ts);
#pragma unroll
  for (int i = 0; i < 4; ++i) {
    int idx = base + i;
    if (idx < N) {
      rowptr[idx] = run;
      cursor[idx] = run;
    }
    run += v[i];
  }
  if (N - 1 >= base && N - 1 < base + 4) rowptr[N] = run;
}

__global__ void scatter_kernel(const int* __restrict__ ei, int E, int N,
                               int* __restrict__ cursor, int* __restrict__ srcs) {
  int e = blockIdx.x * blockDim.x + threadIdx.x;
  if (e >= E + N) return;
  int s = (e < E) ? ei[e] : (e - E);
  int d = (e < E) ? ei[E + e] : (e - E);
  int pos = atomicAdd(&cursor[d], 1);
  srcs[pos] = s;
}

// ---------------- layer-1 gather with fused segment softmax ----------------
// wave per node; 4 x 16-lane head groups. Phases: (A) group max, (B) group
// exp-sum, (C) weighted gather with inline w. Fuses +b1 and ELU, bf16 out.
__global__ __launch_bounds__(256) void gather1_kernel(const u16* __restrict__ h1b,
                                                      const int* __restrict__ rowptr,
                                                      const int* __restrict__ srcs,
                                                      const float* __restrict__ as1,
                                                      const float* __restrict__ ad1,
                                                      const float* __restrict__ b1,
                                                      u16* __restrict__ act1b, int N) {
  const int wave = threadIdx.x >> 6, lane = threadIdx.x & 63;
  const int n = blockIdx.x * 4 + wave;
  if (n >= N) return;
  const int h = lane >> 4, l15 = lane & 15;
  const int beg = rowptr[n], end = rowptr[n + 1];
  const float ad = ad1[(size_t)n * 4 + h];
  // A: segment max over this head
  float m = -1e30f;
  for (int j0 = beg; j0 < end; j0 += 16) {
    int j = j0 + l15;
    if (j < end) m = fmaxf(m, lrelu(as1[(size_t)srcs[j] * 4 + h] + ad));
  }
#pragma unroll
  for (int off = 1; off < 16; off <<= 1) m = fmaxf(m, __shfl_xor(m, off));
  // B: exp-sum
  float s = 0.f;
  for (int j0 = beg; j0 < end; j0 += 16) {
    int j = j0 + l15;
    if (j < end) s += __expf(lrelu(as1[(size_t)srcs[j] * 4 + h] + ad) - m);
  }
#pragma unroll
  for (int off = 1; off < 16; off <<= 1) s += __shfl_xor(s, off);
  const float rs = 1.f / (s + SM_EPS);
  // C: weighted gather (as1 reads now L1/L2-hot, broadcast within group)
  float4 acc = make_float4(0.f, 0.f, 0.f, 0.f);
  int j = beg;
  for (; j + 3 < end; j += 4) {
    int s0 = srcs[j], s1 = srcs[j + 1], s2 = srcs[j + 2], s3 = srcs[j + 3];
    float w0 = __expf(lrelu(as1[(size_t)s0 * 4 + h] + ad) - m) * rs;
    float w1 = __expf(lrelu(as1[(size_t)s1 * 4 + h] + ad) - m) * rs;
    float w2 = __expf(lrelu(as1[(size_t)s2 * 4 + h] + ad) - m) * rs;
    float w3 = __expf(lrelu(as1[(size_t)s3 * 4 + h] + ad) - m) * rs;
    ushort4 v0 = *reinterpret_cast<const ushort4*>(&h1b[(size_t)s0 * 256 + lane * 4]);
    ushort4 v1 = *reinterpret_cast<const ushort4*>(&h1b[(size_t)s1 * 256 + lane * 4]);
    ushort4 v2 = *reinterpret_cast<const ushort4*>(&h1b[(size_t)s2 * 256 + lane * 4]);
    ushort4 v3 = *reinterpret_cast<const ushort4*>(&h1b[(size_t)s3 * 256 + lane * 4]);
    acc.x = fmaf(w0, bf2f(v0.x), acc.x); acc.y = fmaf(w0, bf2f(v0.y), acc.y);
    acc.z = fmaf(w0, bf2f(v0.z), acc.z); acc.w = fmaf(w0, bf2f(v0.w), acc.w);
    acc.x = fmaf(w1, bf2f(v1.x), acc.x); acc.y = fmaf(w1, bf2f(v1.y), acc.y);
    acc.z = fmaf(w1, bf2f(v1.z), acc.z); acc.w = fmaf(w1, bf2f(v1.w), acc.w);
    acc.x = fmaf(w2, bf2f(v2.x), acc.x); acc.y = fmaf(w2, bf2f(v2.y), acc.y);
    acc.z = fmaf(w2, bf2f(v2.z), acc.z); acc.w = fmaf(w2, bf2f(v2.w), acc.w);
    acc.x = fmaf(w3, bf2f(v3.x), acc.x); acc.y = fmaf(w3, bf2f(v3.y), acc.y);
    acc.z = fmaf(w3, bf2f(v3.z), acc.z); acc.w = fmaf(w3, bf2f(v3.w), acc.w);
  }
  for (; j < end; ++j) {
    int s0 = srcs[j];
    float w0 = __expf(lrelu(as1[(size_t)s0 * 4 + h] + ad) - m) * rs;
    ushort4 v0 = *reinterpret_cast<const ushort4*>(&h1b[(size_t)s0 * 256 + lane * 4]);
    acc.x = fmaf(w0, bf2f(v0.x), acc.x); acc.y = fmaf(w0, bf2f(v0.y), acc.y);
    acc.z = fmaf(w0, bf2f(v0.z), acc.z); acc.w = fmaf(w0, bf2f(v0.w), acc.w);
  }
  float4 bb = *reinterpret_cast<const float4*>(&b1[lane * 4]);
  float4 o;
  o.x = acc.x + bb.x; o.y = acc.y + bb.y; o.z = acc.z + bb.z; o.w = acc.w + bb.w;
  o.x = o.x > 0.f ? o.x : __expf(o.x) - 1.f;
  o.y = o.y > 0.f ? o.y : __expf(o.y) - 1.f;
  o.z = o.z > 0.f ? o.z : __expf(o.z) - 1.f;
  o.w = o.w > 0.f ? o.w : __expf(o.w) - 1.f;
  ushort4 ov;
  ov.x = f2bf(o.x); ov.y = f2bf(o.y); ov.z = f2bf(o.z); ov.w = f2bf(o.w);
  *reinterpret_cast<ushort4*>(&act1b[(size_t)n * 256 + lane * 4]) = ov;
}

// ---------------- layer-2 gather with fused segment softmax (H=1) ----------------
__global__ __launch_bounds__(256) void gather2_kernel(const u16* __restrict__ h2b,
                                                      const int* __restrict__ rowptr,
                                                      const int* __restrict__ srcs,
                                                      const float* __restrict__ as2,
                                                      const float* __restrict__ ad2,
                                                      const float* __restrict__ b2,
                                                      float* __restrict__ out, int N) {
  const int wave = threadIdx.x >> 6, lane = threadIdx.x & 63;
  const int n = blockIdx.x * 4 + wave;
  if (n >= N) return;
  const int g = lane >> 4;
  const int c4 = (lane & 15) * 4;
  const int beg = rowptr[n], end = rowptr[n + 1];
  const float ad = ad2[n];
  // A: segment max (whole wave)
  float m = -1e30f;
  for (int j0 = beg; j0 < end; j0 += 64) {
    int j = j0 + lane;
    if (j < end) m = fmaxf(m, lrelu(as2[srcs[j]] + ad));
  }
#pragma unroll
  for (int off = 1; off < 64; off <<= 1) m = fmaxf(m, __shfl_xor(m, off));
  // B: exp-sum
  float s = 0.f;
  for (int j0 = beg; j0 < end; j0 += 64) {
    int j = j0 + lane;
    if (j < end) s += __expf(lrelu(as2[srcs[j]] + ad) - m);
  }
#pragma unroll
  for (int off = 1; off < 64; off <<= 1) s += __shfl_xor(s, off);
  const float rs = 1.f / (s + SM_EPS);
  // C: weighted gather, 4 edges x 16 lanes
  float4 acc = make_float4(0.f, 0.f, 0.f, 0.f);
  for (int j0 = beg; j0 < end; j0 += 4) {
    int j = j0 + g;
    float w = 0.f;
    int si = 0;
    if (j < end) {
      si = srcs[j];
      w = __expf(lrelu(as2[si] + ad) - m) * rs;
    }
    ushort4 v = *reinterpret_cast<const ushort4*>(&h2b[(size_t)si * 64 + c4]);
    acc.x = fmaf(w, bf2f(v.x), acc.x); acc.y = fmaf(w, bf2f(v.y), acc.y);
    acc.z = fmaf(w, bf2f(v.z), acc.z); acc.w = fmaf(w, bf2f(v.w), acc.w);
  }
#pragma unroll
  for (int off = 16; off <= 32; off <<= 1) {
    acc.x += __shfl_xor(acc.x, off);
    acc.y += __shfl_xor(acc.y, off);
    acc.z += __shfl_xor(acc.z, off);
    acc.w += __shfl_xor(acc.w, off);
  }
  if (lane < 16) {
    float4 bb = *reinterpret_cast<const float4*>(&b2[c4]);
    float4 o = make_float4(acc.x + bb.x, acc.y + bb.y, acc.z + bb.z, acc.w + bb.w);
    *reinterpret_cast<float4*>(&out[(size_t)n * 64 + c4]) = o;
  }
}

extern "C" void kernel_launch(void* const* d_in, const int* in_sizes, int n_in,
                              void* d_out, int out_size, void* d_ws, size_t ws_size,
                              hipStream_t stream) {
  const float* x      = (const float*)d_in[0];
  const int*   ei     = (const int*)d_in[1];
  const float* W1     = (const float*)d_in[2];
  const float* a_src1 = (const float*)d_in[3];
  const float* a_dst1 = (const float*)d_in[4];
  const float* b1     = (const float*)d_in[5];
  const float* W2     = (const float*)d_in[6];
  const float* a_src2 = (const float*)d_in[7];
  const float* a_dst2 = (const float*)d_in[8];
  const float* b2     = (const float*)d_in[9];
  float* out = (float*)d_out;

  const int N = in_sizes[0] / 256;  // 50000
  const int E = in_sizes[1] / 2;    // 800000
  const int Etot = E + N;

  char* ws = (char*)d_ws;
  size_t off = 0;
  auto alloc = [&](size_t bytes) -> void* {
    off = (off + 255) & ~(size_t)255;
    void* p = ws + off;
    off += bytes;
    return p;
  };
  u16*   h1b    = (u16*)alloc((size_t)N * 256 * 2);
  u16*   act1b  = (u16*)alloc((size_t)N * 256 * 2);
  u16*   h2b    = (u16*)alloc((size_t)N * 64 * 2);
  float* as1    = (float*)alloc((size_t)N * 4 * 4);
  float* ad1    = (float*)alloc((size_t)N * 4 * 4);
  int*   counts = (int*)alloc((size_t)N * 4);
  int*   rowptr = (int*)alloc((size_t)(N + 1) * 4);
  int*   cursor = (int*)alloc((size_t)N * 4);
  int*   srcs   = (int*)alloc((size_t)Etot * 4);
  int*   bsums  = (int*)alloc((size_t)256 * 4);
  float* as2 = as1;
  float* ad2 = ad1;
  (void)ws_size; (void)n_in; (void)out_size;

  // CSR build
  hipMemsetAsync(counts, 0, (size_t)N * 4, stream);
  int eblocks = (Etot + 255) / 256;
  count_kernel<<<eblocks, 256, 0, stream>>>(ei, E, N, counts);
  const int nb = (N + 1023) / 1024;
  blocksum_kernel<<<nb, 256, 0, stream>>>(counts, bsums, N);
  scanbsums_kernel<<<1, 64, 0, stream>>>(bsums, nb);
  scanfinal_kernel<<<nb, 256, 0, stream>>>(counts, bsums, rowptr, cursor, N);
  scatter_kernel<<<eblocks, 256, 0, stream>>>(ei, E, N, cursor, srcs);

  const int gblocks = (N + 63) / 64;

  // Layer 1
  gemm_mfma<256, 1, 4, 0, 4><<<gblocks, 256, 0, stream>>>(x, W1, h1b, a_src1, a_dst1,
                                                          as1, ad1, N);
  gather1_kernel<<<(N + 3) / 4, 256, 0, stream>>>(h1b, rowptr, srcs, as1, ad1, b1, act1b, N);

  // Layer 2
  gemm_mfma<64, 2, 2, 1, 1><<<gblocks, 256, 0, stream>>>(act1b, W2, h2b, a_src2, a_dst2,
                                                         as2, ad2, N);
  gather2_kernel<<<(N + 3) / 4, 256, 0, stream>>>(h2b, rowptr, srcs, as2, ad2, b2, out, N);
}

// Round 7
// 261.143 us; speedup vs baseline: 1.1714x; 1.1000x over previous
//
#include <hip/hip_runtime.h>
#include <hip/hip_bf16.h>

// GAT encoder, 2 layers, MFMA GEMMs with fused attn-logit epilogue, and
// gathers with fully fused segment-softmax held in registers (load-once,
// exp-once, shfl-share).
// L1: h1=x@W1^T (N,4,64) bf16 + as1/ad1; gather1: softmax+agg+b1+ELU -> act1 bf16.
// L2: h2=act1@W2^T (N,64) bf16 + as2/ad2; gather2: softmax+agg+b2 -> out fp32.
// N=50000, E=800000 (+N self-loops), K=256.

#define NEG_SLOPE 0.2f
#define SM_EPS 1e-16f

typedef unsigned short u16;
typedef unsigned int u32;
typedef __attribute__((ext_vector_type(8))) short short8v;
typedef __attribute__((ext_vector_type(4))) float f32x4;

__device__ __forceinline__ float bf2f(u16 u) { return __uint_as_float(((u32)u) << 16); }
__device__ __forceinline__ u16 f2bf(float f) {
  u32 u = __float_as_uint(f);
  u = (u + 0x7FFFu + ((u >> 16) & 1u)) >> 16;
  return (u16)u;
}
__device__ __forceinline__ float lrelu(float e) { return e > 0.f ? e : NEG_SLOPE * e; }

// ---------------- MFMA GEMM + fused attn-logit epilogue ----------------
template <int BN, int WGM, int WGN, int ABF16, int HEADS>
__global__ __launch_bounds__(256, 2) void gemm_mfma(const void* __restrict__ Av,
                                                    const float* __restrict__ B,
                                                    u16* __restrict__ C,
                                                    const float* __restrict__ a_src,
                                                    const float* __restrict__ a_dst,
                                                    float* __restrict__ as_out,
                                                    float* __restrict__ ad_out, int M) {
  constexpr int K = 256, BK = 128, BM = 64;
  constexpr int WM = BM / WGM, WN = BN / WGN;
  constexpr int MF = WM / 16, NF = WN / 16;
  __shared__ short lds[(BM + BN) * BK];
  short* Al = lds;
  short* Bl = lds + BM * BK;
  const int t = threadIdx.x;
  const int wid = t >> 6, lane = t & 63;
  const int wm = wid / WGN, wn = wid % WGN;
  const int row0 = blockIdx.x * BM;
  const int l15 = lane & 15, l4 = lane >> 4;
  f32x4 acc[MF][NF] = {};
  for (int k0 = 0; k0 < K; k0 += BK) {
    for (int g = t; g < BM * 16; g += 256) {
      int row = g >> 4, c = g & 15;
      int gr = row0 + row;
      short8v v;
      if (ABF16) {
        if (gr < M)
          v = *reinterpret_cast<const short8v*>((const short*)Av + (size_t)gr * K + k0 + c * 8);
        else
          v = (short8v)(short)0;
      } else {
        if (gr < M) {
          const float* ap = (const float*)Av + (size_t)gr * K + k0 + c * 8;
          float4 f0 = *reinterpret_cast<const float4*>(ap);
          float4 f1 = *reinterpret_cast<const float4*>(ap + 4);
          v[0] = (short)f2bf(f0.x); v[1] = (short)f2bf(f0.y);
          v[2] = (short)f2bf(f0.z); v[3] = (short)f2bf(f0.w);
          v[4] = (short)f2bf(f1.x); v[5] = (short)f2bf(f1.y);
          v[6] = (short)f2bf(f1.z); v[7] = (short)f2bf(f1.w);
        } else {
          v = (short8v)(short)0;
        }
      }
      *reinterpret_cast<short8v*>(&Al[row * BK + ((c * 8) ^ ((row & 7) << 3))]) = v;
    }
    for (int g = t; g < BN * 16; g += 256) {
      int row = g >> 4, c = g & 15;
      const float* bp = B + (size_t)row * K + k0 + c * 8;
      float4 f0 = *reinterpret_cast<const float4*>(bp);
      float4 f1 = *reinterpret_cast<const float4*>(bp + 4);
      short8v v;
      v[0] = (short)f2bf(f0.x); v[1] = (short)f2bf(f0.y);
      v[2] = (short)f2bf(f0.z); v[3] = (short)f2bf(f0.w);
      v[4] = (short)f2bf(f1.x); v[5] = (short)f2bf(f1.y);
      v[6] = (short)f2bf(f1.z); v[7] = (short)f2bf(f1.w);
      *reinterpret_cast<short8v*>(&Bl[row * BK + ((c * 8) ^ ((row & 7) << 3))]) = v;
    }
    __syncthreads();
#pragma unroll
    for (int ks = 0; ks < BK / 32; ++ks) {
      short8v af[MF], bfr[NF];
#pragma unroll
      for (int fm = 0; fm < MF; ++fm) {
        int row = wm * WM + fm * 16 + l15;
        int col = (ks * 32 + l4 * 8) ^ ((row & 7) << 3);
        af[fm] = *reinterpret_cast<const short8v*>(&Al[row * BK + col]);
      }
#pragma unroll
      for (int fn = 0; fn < NF; ++fn) {
        int row = wn * WN + fn * 16 + l15;
        int col = (ks * 32 + l4 * 8) ^ ((row & 7) << 3);
        bfr[fn] = *reinterpret_cast<const short8v*>(&Bl[row * BK + col]);
      }
#pragma unroll
      for (int fm = 0; fm < MF; ++fm)
#pragma unroll
        for (int fn = 0; fn < NF; ++fn)
          acc[fm][fn] =
              __builtin_amdgcn_mfma_f32_16x16x32_bf16(af[fm], bfr[fn], acc[fm][fn], 0, 0, 0);
    }
    __syncthreads();
  }
#pragma unroll
  for (int fm = 0; fm < MF; ++fm) {
#pragma unroll
    for (int fn = 0; fn < NF; ++fn) {
      int r0 = row0 + wm * WM + fm * 16 + l4 * 4;
      int col = wn * WN + fn * 16 + l15;
#pragma unroll
      for (int r = 0; r < 4; ++r)
        if (r0 + r < M) C[(size_t)(r0 + r) * BN + col] = f2bf(acc[fm][fn][r]);
    }
  }
  float asv[NF], adv[NF];
#pragma unroll
  for (int fn = 0; fn < NF; ++fn) {
    asv[fn] = a_src[wn * WN + fn * 16 + l15];
    adv[fn] = a_dst[wn * WN + fn * 16 + l15];
  }
  if (HEADS == 4) {
#pragma unroll
    for (int fm = 0; fm < MF; ++fm) {
#pragma unroll
      for (int r = 0; r < 4; ++r) {
        float ps = 0.f, pd = 0.f;
#pragma unroll
        for (int fn = 0; fn < NF; ++fn) {
          ps = fmaf(acc[fm][fn][r], asv[fn], ps);
          pd = fmaf(acc[fm][fn][r], adv[fn], pd);
        }
#pragma unroll
        for (int off = 1; off < 16; off <<= 1) {
          ps += __shfl_xor(ps, off);
          pd += __shfl_xor(pd, off);
        }
        if (l15 == 0) {
          int row = row0 + wm * WM + fm * 16 + l4 * 4 + r;
          if (row < M) {
            as_out[(size_t)row * 4 + wn] = ps;
            ad_out[(size_t)row * 4 + wn] = pd;
          }
        }
      }
    }
  } else {
    float* redAs = (float*)lds;
    float* redAd = redAs + WGM * WGN * WM;
#pragma unroll
    for (int fm = 0; fm < MF; ++fm) {
#pragma unroll
      for (int r = 0; r < 4; ++r) {
        float ps = 0.f, pd = 0.f;
#pragma unroll
        for (int fn = 0; fn < NF; ++fn) {
          ps = fmaf(acc[fm][fn][r], asv[fn], ps);
          pd = fmaf(acc[fm][fn][r], adv[fn], pd);
        }
#pragma unroll
        for (int off = 1; off < 16; off <<= 1) {
          ps += __shfl_xor(ps, off);
          pd += __shfl_xor(pd, off);
        }
        if (l15 == 0) {
          int rl = fm * 16 + l4 * 4 + r;
          redAs[(wm * WGN + wn) * WM + rl] = ps;
          redAd[(wm * WGN + wn) * WM + rl] = pd;
        }
      }
    }
    __syncthreads();
    if (t < BM) {
      int wmx = t / WM, rl = t % WM;
      float s = 0.f, d = 0.f;
      for (int w = 0; w < WGN; ++w) {
        s += redAs[(wmx * WGN + w) * WM + rl];
        d += redAd[(wmx * WGN + w) * WM + rl];
      }
      int row = row0 + t;
      if (row < M) {
        as_out[row] = s;
        ad_out[row] = d;
      }
    }
  }
}

// ---------------- CSR build ----------------
__global__ void count_kernel(const int* __restrict__ ei, int E, int N, int* __restrict__ counts) {
  int e = blockIdx.x * blockDim.x + threadIdx.x;
  if (e >= E + N) return;
  int d = (e < E) ? ei[E + e] : (e - E);
  atomicAdd(&counts[d], 1);
}

__global__ __launch_bounds__(256) void blocksum_kernel(const int* __restrict__ counts,
                                                       int* __restrict__ bsums, int N) {
  const int b = blockIdx.x, t = threadIdx.x;
  const int base = b * 1024 + t * 4;
  int s = 0;
#pragma unroll
  for (int i = 0; i < 4; ++i) {
    int idx = base + i;
    if (idx < N) s += counts[idx];
  }
#pragma unroll
  for (int off = 1; off < 64; off <<= 1) s += __shfl_xor(s, off);
  __shared__ int ws[4];
  if ((t & 63) == 0) ws[t >> 6] = s;
  __syncthreads();
  if (t == 0) bsums[b] = ws[0] + ws[1] + ws[2] + ws[3];
}

__global__ void scanbsums_kernel(int* __restrict__ bsums, int nb) {
  const int t = threadIdx.x;  // 64
  int carry = 0;
  for (int base = 0; base < nb; base += 64) {
    int i = base + t;
    int orig = (i < nb) ? bsums[i] : 0;
    int v = orig;
#pragma unroll
    for (int off = 1; off < 64; off <<= 1) {
      int u = __shfl_up(v, off);
      if (t >= off) v += u;
    }
    if (i < nb) bsums[i] = carry + v - orig;
    carry += __shfl(v, 63);
  }
}

__global__ __launch_bounds__(256) void scanfinal_kernel(const int* __restrict__ counts,
                                                        const int* __restrict__ boffs,
                                                        int* __restrict__ rowptr,
                                                        int* __restrict__ cursor, int N) {
  const int b = blockIdx.x, t = threadIdx.x;
  const int wave = t >> 6, lane = t & 63;
  const int base = b * 1024 + t * 4;
  int v[4];
#pragma unroll
  for (int i = 0; i < 4; ++i) {
    int idx = base + i;
    v[i] = (idx < N) ? counts[idx] : 0;
  }
  int ts = v[0] + v[1] + v[2] + v[3];
  int inc = ts;
#pragma unroll
  for (int off = 1; off < 64; off <<= 1) {
    int u = __shfl_up(inc, off);
    if (lane >= off) inc += u;
  }
  __shared__ int wsum[4];
  if (lane == 63) wsum[wave] = inc;
  __syncthreads();
  int woff = 0;
  for (int w = 0; w < 4; ++w)
    if (w < wave) woff += wsum[w];
  int run = boffs[b] + woff + (inc - ts);
#pragma unroll
  for (int i = 0; i < 4; ++i) {
    int idx = base + i;
    if (idx < N) {
      rowptr[idx] = run;
      cursor[idx] = run;
    }
    run += v[i];
  }
  if (N - 1 >= base && N - 1 < base + 4) rowptr[N] = run;
}

__global__ void scatter_kernel(const int* __restrict__ ei, int E, int N,
                               int* __restrict__ cursor, int* __restrict__ srcs) {
  int e = blockIdx.x * blockDim.x + threadIdx.x;
  if (e >= E + N) return;
  int s = (e < E) ? ei[e] : (e - E);
  int d = (e < E) ? ei[E + e] : (e - E);
  int pos = atomicAdd(&cursor[d], 1);
  srcs[pos] = s;
}

// ---------------- layer-1 gather, register-resident softmax ----------------
// wave per node; 4 x 16-lane head groups. Lane owns edges idx = c*16+l15
// (c<4): as1 loaded ONCE, exp computed ONCE, shared to the group via shfl.
// Fallback recompute path for deg>64 (practically never taken).
__global__ __launch_bounds__(256) void gather1_kernel(const u16* __restrict__ h1b,
                                                      const int* __restrict__ rowptr,
                                                      const int* __restrict__ srcs,
                                                      const float* __restrict__ as1,
                                                      const float* __restrict__ ad1,
                                                      const float* __restrict__ b1,
                                                      u16* __restrict__ act1b, int N) {
  const int wave = threadIdx.x >> 6, lane = threadIdx.x & 63;
  const int n = blockIdx.x * 4 + wave;
  if (n >= N) return;
  const int h = lane >> 4, l15 = lane & 15;
  const int beg = rowptr[n], end = rowptr[n + 1];
  const int deg = end - beg;
  const float ad = ad1[(size_t)n * 4 + h];
  // A: load e once into registers, group max
  float ev[4];
  int sr[4];
  float m = -1e30f;
#pragma unroll
  for (int c = 0; c < 4; ++c) {
    int idx = c * 16 + l15;
    bool ok = idx < deg;
    int si = ok ? srcs[beg + idx] : 0;
    sr[c] = si;
    float e = ok ? lrelu(as1[(size_t)si * 4 + h] + ad) : -1e30f;
    ev[c] = e;
    m = fmaxf(m, e);
  }
  for (int j0 = beg + 64; j0 < end; j0 += 16) {
    int j = j0 + l15;
    if (j < end) m = fmaxf(m, lrelu(as1[(size_t)srcs[j] * 4 + h] + ad));
  }
#pragma unroll
  for (int off = 1; off < 16; off <<= 1) m = fmaxf(m, __shfl_xor(m, off));
  // B: exp once in registers, group sum
  float s = 0.f;
#pragma unroll
  for (int c = 0; c < 4; ++c) {
    ev[c] = __expf(ev[c] - m);  // pad lanes: exp(-inf)=0
    s += ev[c];
  }
  for (int j0 = beg + 64; j0 < end; j0 += 16) {
    int j = j0 + l15;
    if (j < end) s += __expf(lrelu(as1[(size_t)srcs[j] * 4 + h] + ad) - m);
  }
#pragma unroll
  for (int off = 1; off < 16; off <<= 1) s += __shfl_xor(s, off);
  const float rs = 1.f / (s + SM_EPS);
#pragma unroll
  for (int c = 0; c < 4; ++c) ev[c] *= rs;
  // C: weighted gather; w and src come from registers via shfl
  float4 acc = make_float4(0.f, 0.f, 0.f, 0.f);
  const int lim = deg < 64 ? deg : 64;
#pragma unroll
  for (int c = 0; c < 4; ++c) {
    const int base = c * 16;
    if (base < lim) {
      int cnt = lim - base;
      if (cnt > 16) cnt = 16;
      if (cnt == 16) {
#pragma unroll 4
        for (int k = 0; k < 16; ++k) {
          float wk = __shfl(ev[c], h * 16 + k);
          int sk = __shfl(sr[c], h * 16 + k);
          ushort4 v = *reinterpret_cast<const ushort4*>(&h1b[(size_t)sk * 256 + lane * 4]);
          acc.x = fmaf(wk, bf2f(v.x), acc.x); acc.y = fmaf(wk, bf2f(v.y), acc.y);
          acc.z = fmaf(wk, bf2f(v.z), acc.z); acc.w = fmaf(wk, bf2f(v.w), acc.w);
        }
      } else {
        for (int k = 0; k < cnt; ++k) {
          float wk = __shfl(ev[c], h * 16 + k);
          int sk = __shfl(sr[c], h * 16 + k);
          ushort4 v = *reinterpret_cast<const ushort4*>(&h1b[(size_t)sk * 256 + lane * 4]);
          acc.x = fmaf(wk, bf2f(v.x), acc.x); acc.y = fmaf(wk, bf2f(v.y), acc.y);
          acc.z = fmaf(wk, bf2f(v.z), acc.z); acc.w = fmaf(wk, bf2f(v.w), acc.w);
        }
      }
    }
  }
  for (int j = beg + 64; j < end; ++j) {  // rare fallback
    int si = srcs[j];
    float wk = __expf(lrelu(as1[(size_t)si * 4 + h] + ad) - m) * rs;
    ushort4 v = *reinterpret_cast<const ushort4*>(&h1b[(size_t)si * 256 + lane * 4]);
    acc.x = fmaf(wk, bf2f(v.x), acc.x); acc.y = fmaf(wk, bf2f(v.y), acc.y);
    acc.z = fmaf(wk, bf2f(v.z), acc.z); acc.w = fmaf(wk, bf2f(v.w), acc.w);
  }
  float4 bb = *reinterpret_cast<const float4*>(&b1[lane * 4]);
  float4 o;
  o.x = acc.x + bb.x; o.y = acc.y + bb.y; o.z = acc.z + bb.z; o.w = acc.w + bb.w;
  o.x = o.x > 0.f ? o.x : __expf(o.x) - 1.f;
  o.y = o.y > 0.f ? o.y : __expf(o.y) - 1.f;
  o.z = o.z > 0.f ? o.z : __expf(o.z) - 1.f;
  o.w = o.w > 0.f ? o.w : __expf(o.w) - 1.f;
  ushort4 ov;
  ov.x = f2bf(o.x); ov.y = f2bf(o.y); ov.z = f2bf(o.z); ov.w = f2bf(o.w);
  *reinterpret_cast<ushort4*>(&act1b[(size_t)n * 256 + lane * 4]) = ov;
}

// ---------------- layer-2 gather, register-resident softmax (H=1) ----------------
// wave per node; lane owns edge idx=lane (64-edge window). Phase C: 4 edges
// x 16 lanes x 4ch, w/src via shfl.
__global__ __launch_bounds__(256) void gather2_kernel(const u16* __restrict__ h2b,
                                                      const int* __restrict__ rowptr,
                                                      const int* __restrict__ srcs,
                                                      const float* __restrict__ as2,
                                                      const float* __restrict__ ad2,
                                                      const float* __restrict__ b2,
                                                      float* __restrict__ out, int N) {
  const int wave = threadIdx.x >> 6, lane = threadIdx.x & 63;
  const int n = blockIdx.x * 4 + wave;
  if (n >= N) return;
  const int g = lane >> 4;
  const int c4 = (lane & 15) * 4;
  const int beg = rowptr[n], end = rowptr[n + 1];
  const int deg = end - beg;
  const float ad = ad2[n];
  // A: load once, wave max
  bool ok = lane < deg;
  int si = ok ? srcs[beg + lane] : 0;
  float e = ok ? lrelu(as2[si] + ad) : -1e30f;
  float m = e;
  for (int j0 = beg + 64; j0 < end; j0 += 64) {
    int j = j0 + lane;
    if (j < end) m = fmaxf(m, lrelu(as2[srcs[j]] + ad));
  }
#pragma unroll
  for (int off = 1; off < 64; off <<= 1) m = fmaxf(m, __shfl_xor(m, off));
  // B: exp once, wave sum
  float w = __expf(e - m);
  float s = w;
  for (int j0 = beg + 64; j0 < end; j0 += 64) {
    int j = j0 + lane;
    if (j < end) s += __expf(lrelu(as2[srcs[j]] + ad) - m);
  }
#pragma unroll
  for (int off = 1; off < 64; off <<= 1) s += __shfl_xor(s, off);
  const float rs = 1.f / (s + SM_EPS);
  w *= rs;
  // C: 4 edges x 16 lanes
  float4 acc = make_float4(0.f, 0.f, 0.f, 0.f);
  const int lim = deg < 64 ? deg : 64;
  for (int j0 = 0; j0 < lim; j0 += 4) {
    int id = j0 + g;
    float wk = __shfl(w, id & 63);
    int sk = __shfl(si, id & 63);
    if (id >= lim) { wk = 0.f; sk = 0; }
    ushort4 v = *reinterpret_cast<const ushort4*>(&h2b[(size_t)sk * 64 + c4]);
    acc.x = fmaf(wk, bf2f(v.x), acc.x); acc.y = fmaf(wk, bf2f(v.y), acc.y);
    acc.z = fmaf(wk, bf2f(v.z), acc.z); acc.w = fmaf(wk, bf2f(v.w), acc.w);
  }
  for (int j0 = beg + 64; j0 < end; j0 += 4) {  // rare fallback
    int j = j0 + g;
    float wk = 0.f;
    int sk = 0;
    if (j < end) {
      sk = srcs[j];
      wk = __expf(lrelu(as2[sk] + ad) - m) * rs;
    }
    ushort4 v = *reinterpret_cast<const ushort4*>(&h2b[(size_t)sk * 64 + c4]);
    acc.x = fmaf(wk, bf2f(v.x), acc.x); acc.y = fmaf(wk, bf2f(v.y), acc.y);
    acc.z = fmaf(wk, bf2f(v.z), acc.z); acc.w = fmaf(wk, bf2f(v.w), acc.w);
  }
#pragma unroll
  for (int off = 16; off <= 32; off <<= 1) {
    acc.x += __shfl_xor(acc.x, off);
    acc.y += __shfl_xor(acc.y, off);
    acc.z += __shfl_xor(acc.z, off);
    acc.w += __shfl_xor(acc.w, off);
  }
  if (lane < 16) {
    float4 bb = *reinterpret_cast<const float4*>(&b2[c4]);
    float4 o = make_float4(acc.x + bb.x, acc.y + bb.y, acc.z + bb.z, acc.w + bb.w);
    *reinterpret_cast<float4*>(&out[(size_t)n * 64 + c4]) = o;
  }
}

extern "C" void kernel_launch(void* const* d_in, const int* in_sizes, int n_in,
                              void* d_out, int out_size, void* d_ws, size_t ws_size,
                              hipStream_t stream) {
  const float* x      = (const float*)d_in[0];
  const int*   ei     = (const int*)d_in[1];
  const float* W1     = (const float*)d_in[2];
  const float* a_src1 = (const float*)d_in[3];
  const float* a_dst1 = (const float*)d_in[4];
  const float* b1     = (const float*)d_in[5];
  const float* W2     = (const float*)d_in[6];
  const float* a_src2 = (const float*)d_in[7];
  const float* a_dst2 = (const float*)d_in[8];
  const float* b2     = (const float*)d_in[9];
  float* out = (float*)d_out;

  const int N = in_sizes[0] / 256;  // 50000
  const int E = in_sizes[1] / 2;    // 800000
  const int Etot = E + N;

  char* ws = (char*)d_ws;
  size_t off = 0;
  auto alloc = [&](size_t bytes) -> void* {
    off = (off + 255) & ~(size_t)255;
    void* p = ws + off;
    off += bytes;
    return p;
  };
  u16*   h1b    = (u16*)alloc((size_t)N * 256 * 2);
  u16*   act1b  = (u16*)alloc((size_t)N * 256 * 2);
  u16*   h2b    = (u16*)alloc((size_t)N * 64 * 2);
  float* as1    = (float*)alloc((size_t)N * 4 * 4);
  float* ad1    = (float*)alloc((size_t)N * 4 * 4);
  int*   counts = (int*)alloc((size_t)N * 4);
  int*   rowptr = (int*)alloc((size_t)(N + 1) * 4);
  int*   cursor = (int*)alloc((size_t)N * 4);
  int*   srcs   = (int*)alloc((size_t)Etot * 4);
  int*   bsums  = (int*)alloc((size_t)256 * 4);
  float* as2 = as1;
  float* ad2 = ad1;
  (void)ws_size; (void)n_in; (void)out_size;

  // CSR build
  hipMemsetAsync(counts, 0, (size_t)N * 4, stream);
  int eblocks = (Etot + 255) / 256;
  count_kernel<<<eblocks, 256, 0, stream>>>(ei, E, N, counts);
  const int nb = (N + 1023) / 1024;
  blocksum_kernel<<<nb, 256, 0, stream>>>(counts, bsums, N);
  scanbsums_kernel<<<1, 64, 0, stream>>>(bsums, nb);
  scanfinal_kernel<<<nb, 256, 0, stream>>>(counts, bsums, rowptr, cursor, N);
  scatter_kernel<<<eblocks, 256, 0, stream>>>(ei, E, N, cursor, srcs);

  const int gblocks = (N + 63) / 64;

  // Layer 1
  gemm_mfma<256, 1, 4, 0, 4><<<gblocks, 256, 0, stream>>>(x, W1, h1b, a_src1, a_dst1,
                                                          as1, ad1, N);
  gather1_kernel<<<(N + 3) / 4, 256, 0, stream>>>(h1b, rowptr, srcs, as1, ad1, b1, act1b, N);

  // Layer 2
  gemm_mfma<64, 2, 2, 1, 1><<<gblocks, 256, 0, stream>>>(act1b, W2, h2b, a_src2, a_dst2,
                                                         as2, ad2, N);
  gather2_kernel<<<(N + 3) / 4, 256, 0, stream>>>(h2b, rowptr, srcs, as2, ad2, b2, out, N);
}

// Round 8
// 207.564 us; speedup vs baseline: 1.4737x; 1.2581x over previous
//
#include <hip/hip_runtime.h>
#include <hip/hip_bf16.h>

// GAT encoder, 2 layers, MFMA GEMMs (BK=64, high occupancy) with fused
// attn-logit epilogue; gathers with register-resident fused segment-softmax.
// CSR build: count(+rank) -> blocksum -> scanfinal(inline prefix) -> scatter
// (rank-based, no atomics).
// N=50000, E=800000 (+N self-loops), K=256.

#define NEG_SLOPE 0.2f
#define SM_EPS 1e-16f

typedef unsigned short u16;
typedef unsigned int u32;
typedef __attribute__((ext_vector_type(8))) short short8v;
typedef __attribute__((ext_vector_type(4))) float f32x4;

__device__ __forceinline__ float bf2f(u16 u) { return __uint_as_float(((u32)u) << 16); }
__device__ __forceinline__ u16 f2bf(float f) {
  u32 u = __float_as_uint(f);
  u = (u + 0x7FFFu + ((u >> 16) & 1u)) >> 16;
  return (u16)u;
}
__device__ __forceinline__ float lrelu(float e) { return e > 0.f ? e : NEG_SLOPE * e; }

// ---------------- MFMA GEMM + fused attn-logit epilogue (BK=64) ----------------
template <int BN, int WGM, int WGN, int ABF16, int HEADS>
__global__ __launch_bounds__(256, 2) void gemm_mfma(const void* __restrict__ Av,
                                                    const float* __restrict__ B,
                                                    u16* __restrict__ C,
                                                    const float* __restrict__ a_src,
                                                    const float* __restrict__ a_dst,
                                                    float* __restrict__ as_out,
                                                    float* __restrict__ ad_out, int M) {
  constexpr int K = 256, BK = 64, BM = 64;
  constexpr int WM = BM / WGM, WN = BN / WGN;
  constexpr int MF = WM / 16, NF = WN / 16;
  __shared__ short lds[(BM + BN) * BK];
  short* Al = lds;
  short* Bl = lds + BM * BK;
  const int t = threadIdx.x;
  const int wid = t >> 6, lane = t & 63;
  const int wm = wid / WGN, wn = wid % WGN;
  const int row0 = blockIdx.x * BM;
  const int l15 = lane & 15, l4 = lane >> 4;
  f32x4 acc[MF][NF] = {};
  for (int k0 = 0; k0 < K; k0 += BK) {
    // stage A: BM rows x 64 k, 8 granules of short8 per row
    for (int g = t; g < BM * 8; g += 256) {
      int row = g >> 3, c = g & 7;
      int gr = row0 + row;
      short8v v;
      if (ABF16) {
        if (gr < M)
          v = *reinterpret_cast<const short8v*>((const short*)Av + (size_t)gr * K + k0 + c * 8);
        else
          v = (short8v)(short)0;
      } else {
        if (gr < M) {
          const float* ap = (const float*)Av + (size_t)gr * K + k0 + c * 8;
          float4 f0 = *reinterpret_cast<const float4*>(ap);
          float4 f1 = *reinterpret_cast<const float4*>(ap + 4);
          v[0] = (short)f2bf(f0.x); v[1] = (short)f2bf(f0.y);
          v[2] = (short)f2bf(f0.z); v[3] = (short)f2bf(f0.w);
          v[4] = (short)f2bf(f1.x); v[5] = (short)f2bf(f1.y);
          v[6] = (short)f2bf(f1.z); v[7] = (short)f2bf(f1.w);
        } else {
          v = (short8v)(short)0;
        }
      }
      *reinterpret_cast<short8v*>(&Al[row * BK + ((c * 8) ^ ((row & 7) << 3))]) = v;
    }
    // stage B: BN rows x 64 k
    for (int g = t; g < BN * 8; g += 256) {
      int row = g >> 3, c = g & 7;
      const float* bp = B + (size_t)row * K + k0 + c * 8;
      float4 f0 = *reinterpret_cast<const float4*>(bp);
      float4 f1 = *reinterpret_cast<const float4*>(bp + 4);
      short8v v;
      v[0] = (short)f2bf(f0.x); v[1] = (short)f2bf(f0.y);
      v[2] = (short)f2bf(f0.z); v[3] = (short)f2bf(f0.w);
      v[4] = (short)f2bf(f1.x); v[5] = (short)f2bf(f1.y);
      v[6] = (short)f2bf(f1.z); v[7] = (short)f2bf(f1.w);
      *reinterpret_cast<short8v*>(&Bl[row * BK + ((c * 8) ^ ((row & 7) << 3))]) = v;
    }
    __syncthreads();
#pragma unroll
    for (int ks = 0; ks < BK / 32; ++ks) {
      short8v af[MF], bfr[NF];
#pragma unroll
      for (int fm = 0; fm < MF; ++fm) {
        int row = wm * WM + fm * 16 + l15;
        int col = (ks * 32 + l4 * 8) ^ ((row & 7) << 3);
        af[fm] = *reinterpret_cast<const short8v*>(&Al[row * BK + col]);
      }
#pragma unroll
      for (int fn = 0; fn < NF; ++fn) {
        int row = wn * WN + fn * 16 + l15;
        int col = (ks * 32 + l4 * 8) ^ ((row & 7) << 3);
        bfr[fn] = *reinterpret_cast<const short8v*>(&Bl[row * BK + col]);
      }
#pragma unroll
      for (int fm = 0; fm < MF; ++fm)
#pragma unroll
        for (int fn = 0; fn < NF; ++fn)
          acc[fm][fn] =
              __builtin_amdgcn_mfma_f32_16x16x32_bf16(af[fm], bfr[fn], acc[fm][fn], 0, 0, 0);
    }
    __syncthreads();
  }
#pragma unroll
  for (int fm = 0; fm < MF; ++fm) {
#pragma unroll
    for (int fn = 0; fn < NF; ++fn) {
      int r0 = row0 + wm * WM + fm * 16 + l4 * 4;
      int col = wn * WN + fn * 16 + l15;
#pragma unroll
      for (int r = 0; r < 4; ++r)
        if (r0 + r < M) C[(size_t)(r0 + r) * BN + col] = f2bf(acc[fm][fn][r]);
    }
  }
  float asv[NF], adv[NF];
#pragma unroll
  for (int fn = 0; fn < NF; ++fn) {
    asv[fn] = a_src[wn * WN + fn * 16 + l15];
    adv[fn] = a_dst[wn * WN + fn * 16 + l15];
  }
  if (HEADS == 4) {
#pragma unroll
    for (int fm = 0; fm < MF; ++fm) {
#pragma unroll
      for (int r = 0; r < 4; ++r) {
        float ps = 0.f, pd = 0.f;
#pragma unroll
        for (int fn = 0; fn < NF; ++fn) {
          ps = fmaf(acc[fm][fn][r], asv[fn], ps);
          pd = fmaf(acc[fm][fn][r], adv[fn], pd);
        }
#pragma unroll
        for (int off = 1; off < 16; off <<= 1) {
          ps += __shfl_xor(ps, off);
          pd += __shfl_xor(pd, off);
        }
        if (l15 == 0) {
          int row = row0 + wm * WM + fm * 16 + l4 * 4 + r;
          if (row < M) {
            as_out[(size_t)row * 4 + wn] = ps;
            ad_out[(size_t)row * 4 + wn] = pd;
          }
        }
      }
    }
  } else {
    float* redAs = (float*)lds;
    float* redAd = redAs + WGM * WGN * WM;
#pragma unroll
    for (int fm = 0; fm < MF; ++fm) {
#pragma unroll
      for (int r = 0; r < 4; ++r) {
        float ps = 0.f, pd = 0.f;
#pragma unroll
        for (int fn = 0; fn < NF; ++fn) {
          ps = fmaf(acc[fm][fn][r], asv[fn], ps);
          pd = fmaf(acc[fm][fn][r], adv[fn], pd);
        }
#pragma unroll
        for (int off = 1; off < 16; off <<= 1) {
          ps += __shfl_xor(ps, off);
          pd += __shfl_xor(pd, off);
        }
        if (l15 == 0) {
          int rl = fm * 16 + l4 * 4 + r;
          redAs[(wm * WGN + wn) * WM + rl] = ps;
          redAd[(wm * WGN + wn) * WM + rl] = pd;
        }
      }
    }
    __syncthreads();
    if (t < BM) {
      int wmx = t / WM, rl = t % WM;
      float s = 0.f, d = 0.f;
      for (int w = 0; w < WGN; ++w) {
        s += redAs[(wmx * WGN + w) * WM + rl];
        d += redAd[(wmx * WGN + w) * WM + rl];
      }
      int row = row0 + t;
      if (row < M) {
        as_out[row] = s;
        ad_out[row] = d;
      }
    }
  }
}

// ---------------- CSR build ----------------
// count + per-edge rank (atomicAdd return value)
__global__ void count_kernel(const int* __restrict__ ei, int E, int N,
                             int* __restrict__ counts, int* __restrict__ rank) {
  int e = blockIdx.x * blockDim.x + threadIdx.x;
  if (e >= E + N) return;
  int d = (e < E) ? ei[E + e] : (e - E);
  rank[e] = atomicAdd(&counts[d], 1);
}

__global__ __launch_bounds__(256) void blocksum_kernel(const int* __restrict__ counts,
                                                       int* __restrict__ bsums, int N) {
  const int b = blockIdx.x, t = threadIdx.x;
  const int base = b * 1024 + t * 4;
  int s = 0;
#pragma unroll
  for (int i = 0; i < 4; ++i) {
    int idx = base + i;
    if (idx < N) s += counts[idx];
  }
#pragma unroll
  for (int off = 1; off < 64; off <<= 1) s += __shfl_xor(s, off);
  __shared__ int ws[4];
  if ((t & 63) == 0) ws[t >> 6] = s;
  __syncthreads();
  if (t == 0) bsums[b] = ws[0] + ws[1] + ws[2] + ws[3];
}

// per-block rescan; block offset computed inline from raw bsums (nb small)
__global__ __launch_bounds__(256) void scanfinal_kernel(const int* __restrict__ counts,
                                                        const int* __restrict__ bsums,
                                                        int* __restrict__ rowptr,
                                                        int N, int nb) {
  const int b = blockIdx.x, t = threadIdx.x;
  const int wave = t >> 6, lane = t & 63;
  __shared__ int boff_s;
  if (t < 64) {
    int s = 0;
    for (int base = 0; base < nb; base += 64) {
      int i = base + lane;
      s += (i < nb && i < b) ? bsums[i] : 0;
    }
#pragma unroll
    for (int off = 1; off < 64; off <<= 1) s += __shfl_xor(s, off);
    if (lane == 0) boff_s = s;
  }
  const int base = b * 1024 + t * 4;
  int v[4];
#pragma unroll
  for (int i = 0; i < 4; ++i) {
    int idx = base + i;
    v[i] = (idx < N) ? counts[idx] : 0;
  }
  int ts = v[0] + v[1] + v[2] + v[3];
  int inc = ts;
#pragma unroll
  for (int off = 1; off < 64; off <<= 1) {
    int u = __shfl_up(inc, off);
    if (lane >= off) inc += u;
  }
  __shared__ int wsum[4];
  if (lane == 63) wsum[wave] = inc;
  __syncthreads();
  int woff = 0;
  for (int w = 0; w < 4; ++w)
    if (w < wave) woff += wsum[w];
  int run = boff_s + woff + (inc - ts);
#pragma unroll
  for (int i = 0; i < 4; ++i) {
    int idx = base + i;
    if (idx < N) rowptr[idx] = run;
    run += v[i];
  }
  if (N - 1 >= base && N - 1 < base + 4) rowptr[N] = run;
}

// rank-based scatter: no atomics
__global__ void scatter_kernel(const int* __restrict__ ei, int E, int N,
                               const int* __restrict__ rowptr, const int* __restrict__ rank,
                               int* __restrict__ srcs) {
  int e = blockIdx.x * blockDim.x + threadIdx.x;
  if (e >= E + N) return;
  int s = (e < E) ? ei[e] : (e - E);
  int d = (e < E) ? ei[E + e] : (e - E);
  srcs[rowptr[d] + rank[e]] = s;
}

// ---------------- layer-1 gather, register-resident softmax ----------------
__global__ __launch_bounds__(256) void gather1_kernel(const u16* __restrict__ h1b,
                                                      const int* __restrict__ rowptr,
                                                      const int* __restrict__ srcs,
                                                      const float* __restrict__ as1,
                                                      const float* __restrict__ ad1,
                                                      const float* __restrict__ b1,
                                                      u16* __restrict__ act1b, int N) {
  const int wave = threadIdx.x >> 6, lane = threadIdx.x & 63;
  const int n = blockIdx.x * 4 + wave;
  if (n >= N) return;
  const int h = lane >> 4, l15 = lane & 15;
  const int beg = rowptr[n], end = rowptr[n + 1];
  const int deg = end - beg;
  const float ad = ad1[(size_t)n * 4 + h];
  float ev[4];
  int sr[4];
  float m = -1e30f;
#pragma unroll
  for (int c = 0; c < 4; ++c) {
    int idx = c * 16 + l15;
    bool ok = idx < deg;
    int si = ok ? srcs[beg + idx] : 0;
    sr[c] = si;
    float e = ok ? lrelu(as1[(size_t)si * 4 + h] + ad) : -1e30f;
    ev[c] = e;
    m = fmaxf(m, e);
  }
  for (int j0 = beg + 64; j0 < end; j0 += 16) {
    int j = j0 + l15;
    if (j < end) m = fmaxf(m, lrelu(as1[(size_t)srcs[j] * 4 + h] + ad));
  }
#pragma unroll
  for (int off = 1; off < 16; off <<= 1) m = fmaxf(m, __shfl_xor(m, off));
  float s = 0.f;
#pragma unroll
  for (int c = 0; c < 4; ++c) {
    ev[c] = __expf(ev[c] - m);
    s += ev[c];
  }
  for (int j0 = beg + 64; j0 < end; j0 += 16) {
    int j = j0 + l15;
    if (j < end) s += __expf(lrelu(as1[(size_t)srcs[j] * 4 + h] + ad) - m);
  }
#pragma unroll
  for (int off = 1; off < 16; off <<= 1) s += __shfl_xor(s, off);
  const float rs = 1.f / (s + SM_EPS);
#pragma unroll
  for (int c = 0; c < 4; ++c) ev[c] *= rs;
  float4 acc = make_float4(0.f, 0.f, 0.f, 0.f);
  const int lim = deg < 64 ? deg : 64;
#pragma unroll
  for (int c = 0; c < 4; ++c) {
    const int base = c * 16;
    if (base < lim) {
      int cnt = lim - base;
      if (cnt > 16) cnt = 16;
      if (cnt == 16) {
#pragma unroll 4
        for (int k = 0; k < 16; ++k) {
          float wk = __shfl(ev[c], h * 16 + k);
          int sk = __shfl(sr[c], h * 16 + k);
          ushort4 v = *reinterpret_cast<const ushort4*>(&h1b[(size_t)sk * 256 + lane * 4]);
          acc.x = fmaf(wk, bf2f(v.x), acc.x); acc.y = fmaf(wk, bf2f(v.y), acc.y);
          acc.z = fmaf(wk, bf2f(v.z), acc.z); acc.w = fmaf(wk, bf2f(v.w), acc.w);
        }
      } else {
        for (int k = 0; k < cnt; ++k) {
          float wk = __shfl(ev[c], h * 16 + k);
          int sk = __shfl(sr[c], h * 16 + k);
          ushort4 v = *reinterpret_cast<const ushort4*>(&h1b[(size_t)sk * 256 + lane * 4]);
          acc.x = fmaf(wk, bf2f(v.x), acc.x); acc.y = fmaf(wk, bf2f(v.y), acc.y);
          acc.z = fmaf(wk, bf2f(v.z), acc.z); acc.w = fmaf(wk, bf2f(v.w), acc.w);
        }
      }
    }
  }
  for (int j = beg + 64; j < end; ++j) {
    int si = srcs[j];
    float wk = __expf(lrelu(as1[(size_t)si * 4 + h] + ad) - m) * rs;
    ushort4 v = *reinterpret_cast<const ushort4*>(&h1b[(size_t)si * 256 + lane * 4]);
    acc.x = fmaf(wk, bf2f(v.x), acc.x); acc.y = fmaf(wk, bf2f(v.y), acc.y);
    acc.z = fmaf(wk, bf2f(v.z), acc.z); acc.w = fmaf(wk, bf2f(v.w), acc.w);
  }
  float4 bb = *reinterpret_cast<const float4*>(&b1[lane * 4]);
  float4 o;
  o.x = acc.x + bb.x; o.y = acc.y + bb.y; o.z = acc.z + bb.z; o.w = acc.w + bb.w;
  o.x = o.x > 0.f ? o.x : __expf(o.x) - 1.f;
  o.y = o.y > 0.f ? o.y : __expf(o.y) - 1.f;
  o.z = o.z > 0.f ? o.z : __expf(o.z) - 1.f;
  o.w = o.w > 0.f ? o.w : __expf(o.w) - 1.f;
  ushort4 ov;
  ov.x = f2bf(o.x); ov.y = f2bf(o.y); ov.z = f2bf(o.z); ov.w = f2bf(o.w);
  *reinterpret_cast<ushort4*>(&act1b[(size_t)n * 256 + lane * 4]) = ov;
}

// ---------------- layer-2 gather, register-resident softmax (H=1) ----------------
__global__ __launch_bounds__(256) void gather2_kernel(const u16* __restrict__ h2b,
                                                      const int* __restrict__ rowptr,
                                                      const int* __restrict__ srcs,
                                                      const float* __restrict__ as2,
                                                      const float* __restrict__ ad2,
                                                      const float* __restrict__ b2,
                                                      float* __restrict__ out, int N) {
  const int wave = threadIdx.x >> 6, lane = threadIdx.x & 63;
  const int n = blockIdx.x * 4 + wave;
  if (n >= N) return;
  const int g = lane >> 4;
  const int c4 = (lane & 15) * 4;
  const int beg = rowptr[n], end = rowptr[n + 1];
  const int deg = end - beg;
  const float ad = ad2[n];
  bool ok = lane < deg;
  int si = ok ? srcs[beg + lane] : 0;
  float e = ok ? lrelu(as2[si] + ad) : -1e30f;
  float m = e;
  for (int j0 = beg + 64; j0 < end; j0 += 64) {
    int j = j0 + lane;
    if (j < end) m = fmaxf(m, lrelu(as2[srcs[j]] + ad));
  }
#pragma unroll
  for (int off = 1; off < 64; off <<= 1) m = fmaxf(m, __shfl_xor(m, off));
  float w = __expf(e - m);
  float s = w;
  for (int j0 = beg + 64; j0 < end; j0 += 64) {
    int j = j0 + lane;
    if (j < end) s += __expf(lrelu(as2[srcs[j]] + ad) - m);
  }
#pragma unroll
  for (int off = 1; off < 64; off <<= 1) s += __shfl_xor(s, off);
  const float rs = 1.f / (s + SM_EPS);
  w *= rs;
  float4 acc = make_float4(0.f, 0.f, 0.f, 0.f);
  const int lim = deg < 64 ? deg : 64;
  for (int j0 = 0; j0 < lim; j0 += 4) {
    int id = j0 + g;
    float wk = __shfl(w, id & 63);
    int sk = __shfl(si, id & 63);
    if (id >= lim) { wk = 0.f; sk = 0; }
    ushort4 v = *reinterpret_cast<const ushort4*>(&h2b[(size_t)sk * 64 + c4]);
    acc.x = fmaf(wk, bf2f(v.x), acc.x); acc.y = fmaf(wk, bf2f(v.y), acc.y);
    acc.z = fmaf(wk, bf2f(v.z), acc.z); acc.w = fmaf(wk, bf2f(v.w), acc.w);
  }
  for (int j0 = beg + 64; j0 < end; j0 += 4) {
    int j = j0 + g;
    float wk = 0.f;
    int sk = 0;
    if (j < end) {
      sk = srcs[j];
      wk = __expf(lrelu(as2[sk] + ad) - m) * rs;
    }
    ushort4 v = *reinterpret_cast<const ushort4*>(&h2b[(size_t)sk * 64 + c4]);
    acc.x = fmaf(wk, bf2f(v.x), acc.x); acc.y = fmaf(wk, bf2f(v.y), acc.y);
    acc.z = fmaf(wk, bf2f(v.z), acc.z); acc.w = fmaf(wk, bf2f(v.w), acc.w);
  }
#pragma unroll
  for (int off = 16; off <= 32; off <<= 1) {
    acc.x += __shfl_xor(acc.x, off);
    acc.y += __shfl_xor(acc.y, off);
    acc.z += __shfl_xor(acc.z, off);
    acc.w += __shfl_xor(acc.w, off);
  }
  if (lane < 16) {
    float4 bb = *reinterpret_cast<const float4*>(&b2[c4]);
    float4 o = make_float4(acc.x + bb.x, acc.y + bb.y, acc.z + bb.z, acc.w + bb.w);
    *reinterpret_cast<float4*>(&out[(size_t)n * 64 + c4]) = o;
  }
}

extern "C" void kernel_launch(void* const* d_in, const int* in_sizes, int n_in,
                              void* d_out, int out_size, void* d_ws, size_t ws_size,
                              hipStream_t stream) {
  const float* x      = (const float*)d_in[0];
  const int*   ei     = (const int*)d_in[1];
  const float* W1     = (const float*)d_in[2];
  const float* a_src1 = (const float*)d_in[3];
  const float* a_dst1 = (const float*)d_in[4];
  const float* b1     = (const float*)d_in[5];
  const float* W2     = (const float*)d_in[6];
  const float* a_src2 = (const float*)d_in[7];
  const float* a_dst2 = (const float*)d_in[8];
  const float* b2     = (const float*)d_in[9];
  float* out = (float*)d_out;

  const int N = in_sizes[0] / 256;  // 50000
  const int E = in_sizes[1] / 2;    // 800000
  const int Etot = E + N;

  char* ws = (char*)d_ws;
  size_t off = 0;
  auto alloc = [&](size_t bytes) -> void* {
    off = (off + 255) & ~(size_t)255;
    void* p = ws + off;
    off += bytes;
    return p;
  };
  u16*   h1b    = (u16*)alloc((size_t)N * 256 * 2);
  u16*   act1b  = (u16*)alloc((size_t)N * 256 * 2);
  u16*   h2b    = (u16*)alloc((size_t)N * 64 * 2);
  float* as1    = (float*)alloc((size_t)N * 4 * 4);
  float* ad1    = (float*)alloc((size_t)N * 4 * 4);
  int*   counts = (int*)alloc((size_t)N * 4);
  int*   rowptr = (int*)alloc((size_t)(N + 1) * 4);
  int*   rank   = (int*)alloc((size_t)Etot * 4);
  int*   srcs   = (int*)alloc((size_t)Etot * 4);
  int*   bsums  = (int*)alloc((size_t)256 * 4);
  float* as2 = as1;
  float* ad2 = ad1;
  (void)ws_size; (void)n_in; (void)out_size;

  // CSR build
  hipMemsetAsync(counts, 0, (size_t)N * 4, stream);
  int eblocks = (Etot + 255) / 256;
  count_kernel<<<eblocks, 256, 0, stream>>>(ei, E, N, counts, rank);
  const int nb = (N + 1023) / 1024;
  blocksum_kernel<<<nb, 256, 0, stream>>>(counts, bsums, N);
  scanfinal_kernel<<<nb, 256, 0, stream>>>(counts, bsums, rowptr, N, nb);
  scatter_kernel<<<eblocks, 256, 0, stream>>>(ei, E, N, rowptr, rank, srcs);

  const int gblocks = (N + 63) / 64;

  // Layer 1
  gemm_mfma<256, 1, 4, 0, 4><<<gblocks, 256, 0, stream>>>(x, W1, h1b, a_src1, a_dst1,
                                                          as1, ad1, N);
  gather1_kernel<<<(N + 3) / 4, 256, 0, stream>>>(h1b, rowptr, srcs, as1, ad1, b1, act1b, N);

  // Layer 2
  gemm_mfma<64, 2, 2, 1, 1><<<gblocks, 256, 0, stream>>>(act1b, W2, h2b, a_src2, a_dst2,
                                                         as2, ad2, N);
  gather2_kernel<<<(N + 3) / 4, 256, 0, stream>>>(h2b, rowptr, srcs, as2, ad2, b2, out, N);
}